// Round 7
// baseline (12.195 us; speedup 1.0000x reference)
//
#include <hip/hip_runtime.h>
#include <cmath>

#define BATCH 4
#define SEQLEN 2048
#define DMODEL 64
#define NTOK (BATCH * SEQLEN)          // 8192 tokens
#define TOK_PER_WAVE 4
#define WAVES_PER_BLOCK 8              // 512 threads: ONE block per CU, stage weights once
#define TOK_PER_BLOCK (TOK_PER_WAVE * WAVES_PER_BLOCK)   // 32
#define NBLOCKS (NTOK / TOK_PER_BLOCK)                   // 256 -> 1 block/CU, 8 waves (2/SIMD)

typedef float floatx2 __attribute__((ext_vector_type(2)));

// bf16 round-to-nearest-even (weights are finite; NaN path not needed)
__device__ __forceinline__ unsigned f2bf(float f) {
    unsigned u = __builtin_bit_cast(unsigned, f);
    return (u + 0x7FFFu + ((u >> 16) & 1u)) >> 16;
}
// dword holds bf16(k_even) in lo16, bf16(k_odd) in hi16 -> {even, odd} as f32 pair
__device__ __forceinline__ floatx2 bfpair(unsigned u) {
    floatx2 r;
    r.x = __builtin_bit_cast(float, u << 16);
    r.y = __builtin_bit_cast(float, u & 0xFFFF0000u);
    return r;
}

// v += rotate-right-within-row16(v, N) ; pure VALU (DPP), no LDS pipe
template <int CTRL>
__device__ __forceinline__ float dpp_ror_add(float v) {
    int x = __builtin_bit_cast(int, v);
    int y = __builtin_amdgcn_update_dpp(0, x, CTRL, 0xF, 0xF, true);
    return v + __builtin_bit_cast(float, y);
}

// y[tok, d] = x[tok, d] * softplus(x@W1+b1)[tok, d] * sum_n (x@W2+b2)[tok,n]*(x@W3+b3)[tok,n]
//
// LDS: per matrix 64 rows (channel d) x 32 dwords; dword j of row d holds bf16 of
// k=2j (lo) and k=2j+1 (hi), stored at physical dword  d*32 + 2*((j>>1)^(d&15)) + (j&1).
// -> compute-side ds_read_b64 is conflict-free; staging writes ~4-way (cheap).
__global__ __launch_bounds__(512, 2) void s6_fused_kernel(
    const float* __restrict__ x,
    const float* __restrict__ W1, const float* __restrict__ b1,
    const float* __restrict__ W2, const float* __restrict__ b2,
    const float* __restrict__ W3, const float* __restrict__ b3,
    float* __restrict__ y)
{
    __shared__ unsigned sW[3][DMODEL * 32];   // 3 * 8 KiB = 24 KiB (bf16-packed)

    const int tid  = threadIdx.x;
    const int lane = tid & 63;
    const int wave = tid >> 6;

    // ---- Stage 1: global weight loads. Thread (r, dg) owns dword j=r of channels
    // d = 4*dg..4*dg+3: needs rows k=2r and 2r+1 (two coalesced b128 loads per matrix).
    const int r  = tid >> 4;           // 0..31  (dword index j within a row)
    const int dg = tid & 15;           // d-group
    float4 f0[3], f1[3];
    {
        const float4* g0 = (const float4*)W1;
        const float4* g1 = (const float4*)W2;
        const float4* g2 = (const float4*)W3;
        const int i0 = (2 * r) * 16 + dg, i1 = (2 * r + 1) * 16 + dg;
        f0[0] = g0[i0]; f1[0] = g0[i1];
        f0[1] = g1[i0]; f1[1] = g1[i1];
        f0[2] = g2[i0]; f1[2] = g2[i1];
    }

    // Wave-uniform token base (readfirstlane -> scalar loads of x rows)
    const int tok0 = __builtin_amdgcn_readfirstlane(
        (blockIdx.x * WAVES_PER_BLOCK + wave) * TOK_PER_WAVE);
    const float* __restrict__ xb = x + (size_t)tok0 * DMODEL;

    // Per-lane x values for the final elementwise scale (coalesced)
    float xv[TOK_PER_WAVE];
    #pragma unroll
    for (int t = 0; t < TOK_PER_WAVE; ++t)
        xv[t] = x[(size_t)(tok0 + t) * DMODEL + lane];

    const float bb1 = b1[lane], bb2 = b2[lane], bb3 = b3[lane];

    // ---- Stage 2: pack to bf16 pairs, swizzled scatter into LDS
    #pragma unroll
    for (int m = 0; m < 3; ++m) {
        const float* p0 = (const float*)&f0[m];
        const float* p1 = (const float*)&f1[m];
        #pragma unroll
        for (int jj = 0; jj < 4; ++jj) {
            const int d = dg * 4 + jj;
            const unsigned v = f2bf(p0[jj]) | (f2bf(p1[jj]) << 16);
            sW[m][d * 32 + 2 * ((r >> 1) ^ (d & 15)) + (r & 1)] = v;
        }
    }

    // {even-k, odd-k} partial accumulators (packed f32 FMA)
    floatx2 av1[TOK_PER_WAVE], av2[TOK_PER_WAVE], av3[TOK_PER_WAVE];
    #pragma unroll
    for (int t = 0; t < TOK_PER_WAVE; ++t) {
        av1[t] = (floatx2)(0.f, 0.f);
        av2[t] = (floatx2)(0.f, 0.f);
        av3[t] = (floatx2)(0.f, 0.f);
    }

    __syncthreads();

    // ---- k-loop: per wave 48 ds_read_b64 (conflict-free) + wave-uniform scalar x loads
    //      + packed v_pk_fma_f32 (2 FLOPs/instr)
    const unsigned* __restrict__ r1 = sW[0] + lane * 32;
    const unsigned* __restrict__ r2 = sW[1] + lane * 32;
    const unsigned* __restrict__ r3 = sW[2] + lane * 32;
    const int lsw = lane & 15;

    #pragma unroll
    for (int kk = 0; kk < DMODEL / 4; ++kk) {
        const int off = 2 * (kk ^ lsw);            // swizzled b64 slot; k = 4kk..4kk+3
        const uint2 u1 = *(const uint2*)(r1 + off);
        const uint2 u2 = *(const uint2*)(r2 + off);
        const uint2 u3 = *(const uint2*)(r3 + off);
        const floatx2 wA1 = bfpair(u1.x), wB1 = bfpair(u1.y);   // {k0,k1}, {k2,k3}
        const floatx2 wA2 = bfpair(u2.x), wB2 = bfpair(u2.y);
        const floatx2 wA3 = bfpair(u3.x), wB3 = bfpair(u3.y);
        #pragma unroll
        for (int t = 0; t < TOK_PER_WAVE; ++t) {
            const float* xr = xb + t * DMODEL + kk * 4;   // wave-uniform -> s_load_dwordx4
            floatx2 xA; xA.x = xr[0]; xA.y = xr[1];
            floatx2 xB; xB.x = xr[2]; xB.y = xr[3];
            av1[t] = __builtin_elementwise_fma(xA, wA1, av1[t]);
            av1[t] = __builtin_elementwise_fma(xB, wB1, av1[t]);
            av2[t] = __builtin_elementwise_fma(xA, wA2, av2[t]);
            av2[t] = __builtin_elementwise_fma(xB, wB2, av2[t]);
            av3[t] = __builtin_elementwise_fma(xA, wA3, av3[t]);
            av3[t] = __builtin_elementwise_fma(xB, wB3, av3[t]);
        }
    }

    #pragma unroll
    for (int t = 0; t < TOK_PER_WAVE; ++t) {
        const float a1 = bb1 + av1[t].x + av1[t].y;
        const float a2 = bb2 + av2[t].x + av2[t].y;
        const float a3 = bb3 + av3[t].x + av3[t].y;
        const float delta = log1pf(expf(a1));      // softplus
        float prod = a2 * a3;
        // all-reduce over 64 lanes: 4 DPP row-rotations (VALU) + 2 LDS shuffles
        prod = dpp_ror_add<0x121>(prod);           // ror 1 within row16
        prod = dpp_ror_add<0x122>(prod);           // ror 2
        prod = dpp_ror_add<0x124>(prod);           // ror 4
        prod = dpp_ror_add<0x128>(prod);           // ror 8
        prod += __shfl_xor(prod, 16);
        prod += __shfl_xor(prod, 32);
        y[(size_t)(tok0 + t) * DMODEL + lane] = xv[t] * delta * prod;
    }
}

extern "C" void kernel_launch(void* const* d_in, const int* in_sizes, int n_in,
                              void* d_out, int out_size, void* d_ws, size_t ws_size,
                              hipStream_t stream) {
    const float* x  = (const float*)d_in[0];
    const float* W1 = (const float*)d_in[1];
    const float* b1 = (const float*)d_in[2];
    const float* W2 = (const float*)d_in[3];
    const float* b2 = (const float*)d_in[4];
    const float* W3 = (const float*)d_in[5];
    const float* b3 = (const float*)d_in[6];
    // d_in[7] = A: provably unused (dA * 0.0 == 0 for finite dA)
    float* y = (float*)d_out;

    s6_fused_kernel<<<NBLOCKS, 512, 0, stream>>>(x, W1, b1, W2, b2, W3, b3, y);
}